// Round 1
// baseline (583.241 us; speedup 1.0000x reference)
//
#include <hip/hip_runtime.h>
#include <math.h>

#define BATCH 32
#define A_PER 9
#define FH 100
#define FW 100
#define A_TOT (FH*FW*A_PER)   /* 90000 */
#define KSEL 1000
#define BUFCAP 2048
#define NMS_T 0.7f
#define MIN_SZ 0.001f
#define BBOX_CLIP_F 4.135166556742356f

__device__ __forceinline__ unsigned int f2key(float f) {
    unsigned int u = __float_as_uint(f);
    return u ^ ((u & 0x80000000u) ? 0xFFFFFFFFu : 0x80000000u);
}
__device__ __forceinline__ float key2f(unsigned int k) {
    return __uint_as_float((k & 0x80000000u) ? (k ^ 0x80000000u) : ~k);
}

// ---------------- Kernel 1: exact top-1000 select + sort + decode ----------
__global__ __launch_bounds__(1024) void select_decode_kernel(
    const float* __restrict__ obj,      // [B,9,100,100]
    const float* __restrict__ deltas,   // [B,36,100,100]
    const float* __restrict__ anchors,  // [90000,4]
    const int* __restrict__ imh_p, const int* __restrict__ imw_p,
    float* __restrict__ boxes_ws, float* __restrict__ prob_ws,
    unsigned long long* __restrict__ valid_ws)
{
    const int b = blockIdx.x;
    const int tid = threadIdx.x;
    const float* sc = obj + (size_t)b * A_TOT;

    __shared__ unsigned int hist[256];
    __shared__ unsigned int sh_prefix, sh_want, sh_cnt;
    __shared__ unsigned long long buf[BUFCAP];
    __shared__ unsigned long long vbits[16];

    if (tid == 0) { sh_prefix = 0u; sh_want = KSEL; }

    // ---- radix select: find exact key of the 1000th-largest score ----
    for (int p = 0; p < 4; ++p) {
        for (int i = tid; i < 256; i += 1024) hist[i] = 0u;
        __syncthreads();
        unsigned int prefix = sh_prefix;
        int shift = 24 - 8 * p;
        for (int e = tid; e < A_TOT; e += 1024) {
            unsigned int key = f2key(sc[e]);
            bool ok = true;
            if (p > 0) ok = ((key >> (shift + 8)) == prefix);
            if (ok) atomicAdd(&hist[(key >> shift) & 255u], 1u);
        }
        __syncthreads();
        if (tid == 0) {
            unsigned int want = sh_want, cum = 0;
            for (int d = 255; d >= 0; --d) {
                unsigned int h = hist[d];
                if (cum + h >= want) {
                    sh_prefix = (prefix << 8) | (unsigned int)d;
                    sh_want = want - cum;
                    break;
                }
                cum += h;
            }
        }
        __syncthreads();
    }
    unsigned int T = sh_prefix;   // key of rank-1000 element

    // ---- gather all elements with key >= T (composite 64-bit keys) ----
    if (tid == 0) sh_cnt = 0u;
    __syncthreads();
    for (int e = tid; e < A_TOT; e += 1024) {
        unsigned int key = f2key(sc[e]);
        if (key >= T) {
            unsigned int pos = atomicAdd(&sh_cnt, 1u);
            if (pos < BUFCAP) {
                int a = e / 10000; int rem = e - a * 10000;   // rem = h*100+w
                unsigned int i = (unsigned int)(rem * 9 + a); // flat (h,w,a) index
                buf[pos] = ((unsigned long long)key << 32) | (unsigned int)(~i);
            }
        }
    }
    __syncthreads();
    unsigned int cnt = sh_cnt; if (cnt > BUFCAP) cnt = BUFCAP;
    int n = (cnt <= 1024u) ? 1024 : BUFCAP;
    for (int i = tid; i < BUFCAP; i += 1024) if (i >= (int)cnt) buf[i] = 0ull;

    // ---- bitonic sort descending (score desc, index asc on ties) ----
    for (int k2 = 2; k2 <= n; k2 <<= 1) {
        for (int j = k2 >> 1; j > 0; j >>= 1) {
            __syncthreads();
            for (int idx = tid; idx < n; idx += 1024) {
                int ixj = idx ^ j;
                if (ixj > idx) {
                    unsigned long long x = buf[idx], y = buf[ixj];
                    if (((idx & k2) == 0) ? (x < y) : (x > y)) {
                        buf[idx] = y; buf[ixj] = x;
                    }
                }
            }
        }
    }
    if (tid < 16) vbits[tid] = 0ull;
    __syncthreads();

    // ---- decode + clip + valid for the 1000 winners ----
    float imw = (float)(*imw_p);
    float imh = (float)(*imh_p);
    if (tid < KSEL) {
        int r = tid;
        unsigned long long kv = buf[r];
        unsigned int keyhi = (unsigned int)(kv >> 32);
        unsigned int i = ~((unsigned int)kv);
        float score = key2f(keyhi);
        float prob = 1.0f / (1.0f + expf(-score));

        int a = (int)(i % 9u); int hw = (int)(i / 9u);
        int h = hw / 100, w = hw - 100 * (hw / 100);
        const float* D = deltas + (size_t)b * 36 * 10000;
        int off = h * 100 + w;
        float dx  = D[(a * 4 + 0) * 10000 + off];
        float dy  = D[(a * 4 + 1) * 10000 + off];
        float dwv = fminf(D[(a * 4 + 2) * 10000 + off], BBOX_CLIP_F);
        float dhv = fminf(D[(a * 4 + 3) * 10000 + off], BBOX_CLIP_F);
        const float* anc = anchors + (size_t)i * 4;
        float ax1 = anc[0], ay1 = anc[1], ax2 = anc[2], ay2 = anc[3];
        float aw = ax2 - ax1, ah = ay2 - ay1;
        float acx = ax1 + 0.5f * aw, acy = ay1 + 0.5f * ah;
        float pcx = dx * aw + acx, pcy = dy * ah + acy;
        float pw = expf(dwv) * aw, ph = expf(dhv) * ah;
        float x1 = pcx - 0.5f * pw, y1 = pcy - 0.5f * ph;
        float x2 = pcx + 0.5f * pw, y2 = pcy + 0.5f * ph;
        x1 = fminf(fmaxf(x1, 0.0f), imw);
        y1 = fminf(fmaxf(y1, 0.0f), imh);
        x2 = fminf(fmaxf(x2, 0.0f), imw);
        y2 = fminf(fmaxf(y2, 0.0f), imh);
        bool valid = ((x2 - x1) >= MIN_SZ) && ((y2 - y1) >= MIN_SZ) && (prob >= 0.0f);
        size_t bo = ((size_t)b * KSEL + r) * 4;
        boxes_ws[bo + 0] = x1; boxes_ws[bo + 1] = y1;
        boxes_ws[bo + 2] = x2; boxes_ws[bo + 3] = y2;
        prob_ws[(size_t)b * KSEL + r] = prob;
        if (valid) atomicOr(&vbits[r >> 6], 1ull << (r & 63));
    }
    __syncthreads();
    if (tid < 16) valid_ws[b * 16 + tid] = vbits[tid];
}

// ---------------- Kernel 2: 1000x1000 suppression bitmatrix ----------------
__global__ __launch_bounds__(1024) void mask_kernel(
    const float* __restrict__ boxes_ws, unsigned long long* __restrict__ mask_ws)
{
    const int b = blockIdx.x >> 3;
    const int part = blockIdx.x & 7;
    const int tid = threadIdx.x;
    const int lane = tid & 63;
    const int wv = tid >> 6;          // 0..15
    __shared__ float4 bx[KSEL];
    __shared__ float ar[KSEL];
    for (int r = tid; r < KSEL; r += 1024) {
        float4 v = ((const float4*)boxes_ws)[(size_t)b * KSEL + r];
        bx[r] = v;
        ar[r] = (v.z - v.x) * (v.w - v.y);
    }
    __syncthreads();
    int slot = part * 16 + wv;        // 0..127
    for (int r = slot; r < KSEL; r += 128) {
        float4 a = bx[r];
        float area_a = ar[r];
        unsigned long long* row = mask_ws + ((size_t)b * KSEL + r) * 16;
        int wlo = r >> 6;
        for (int t = 0; t < 16; ++t) {
            if (t < wlo) { if (lane == 0) row[t] = 0ull; continue; }
            int j = (t << 6) | lane;
            bool bit = false;
            if (j > r && j < KSEL) {
                float4 c = bx[j];
                float xx1 = fmaxf(a.x, c.x), yy1 = fmaxf(a.y, c.y);
                float xx2 = fminf(a.z, c.z), yy2 = fminf(a.w, c.w);
                float iw = fmaxf(xx2 - xx1, 0.0f), ih = fmaxf(yy2 - yy1, 0.0f);
                float inter = iw * ih;
                float iou = inter / (area_a + ar[j] - inter + 1e-12f);
                bit = iou > NMS_T;
            }
            unsigned long long m = __ballot(bit);
            if (lane == 0) row[t] = m;
        }
    }
}

// ---------------- Kernel 3: greedy chain + stable compaction ---------------
__global__ __launch_bounds__(256) void nms_out_kernel(
    const float* __restrict__ boxes_ws, const float* __restrict__ prob_ws,
    const unsigned long long* __restrict__ valid_ws,
    const unsigned long long* __restrict__ mask_ws,
    float* __restrict__ out)
{
    const int b = blockIdx.x;
    const int tid = threadIdx.x;
    const int lane = tid & 63;
    __shared__ unsigned long long keep_lds[16];
    __shared__ unsigned int psum[16];

    if (tid < 64) {
        unsigned long long kw = (lane < 16) ? valid_ws[b * 16 + lane] : 0ull;
        const unsigned long long* mrow = mask_ws + (size_t)b * KSEL * 16;
        const int PF = 8;
        unsigned long long pre[PF];
#pragma unroll
        for (int d = 0; d < PF; ++d)
            pre[d] = (lane < 16) ? mrow[d * 16 + lane] : 0ull;
#pragma unroll 8
        for (int i = 0; i < KSEL; ++i) {
            unsigned long long rw = pre[i & (PF - 1)];
            if (i + PF < KSEL)
                pre[i & (PF - 1)] = (lane < 16) ? mrow[(i + PF) * 16 + lane] : 0ull;
            unsigned long long wbits = __shfl(kw, i >> 6);
            if ((wbits >> (i & 63)) & 1ull) kw &= ~rw;
        }
        if (lane < 16) keep_lds[lane] = kw;
    }
    __syncthreads();
    if (tid == 0) {
        unsigned int s = 0;
        for (int wq = 0; wq < 16; ++wq) { psum[wq] = s; s += __popcll(keep_lds[wq]); }
    }
    __syncthreads();

    float* ob = out;                                     // [B,1000,4]
    float* op = out + (size_t)BATCH * KSEL * 4;          // [B,1000]
    float* om = op + (size_t)BATCH * KSEL;               // [B,1000]
    float* obb = ob + (size_t)b * KSEL * 4;
    float* opb = op + (size_t)b * KSEL;
    float* omb = om + (size_t)b * KSEL;

    for (int r = tid; r < KSEL; r += 256) {
        obb[r * 4 + 0] = 0.0f; obb[r * 4 + 1] = 0.0f;
        obb[r * 4 + 2] = 0.0f; obb[r * 4 + 3] = 0.0f;
        opb[r] = 0.0f; omb[r] = 0.0f;
    }
    __syncthreads();
    for (int r = tid; r < KSEL; r += 256) {
        unsigned long long kw = keep_lds[r >> 6];
        if ((kw >> (r & 63)) & 1ull) {
            unsigned int p = psum[r >> 6] + (unsigned int)__popcll(kw & ((1ull << (r & 63)) - 1ull));
            size_t src = ((size_t)b * KSEL + r) * 4;
            obb[p * 4 + 0] = boxes_ws[src + 0];
            obb[p * 4 + 1] = boxes_ws[src + 1];
            obb[p * 4 + 2] = boxes_ws[src + 2];
            obb[p * 4 + 3] = boxes_ws[src + 3];
            opb[p] = prob_ws[(size_t)b * KSEL + r];
            omb[p] = 1.0f;
        }
    }
}

extern "C" void kernel_launch(void* const* d_in, const int* in_sizes, int n_in,
                              void* d_out, int out_size, void* d_ws, size_t ws_size,
                              hipStream_t stream) {
    const float* obj     = (const float*)d_in[0];
    const float* deltas  = (const float*)d_in[1];
    const float* anchors = (const float*)d_in[2];
    const int*   imh     = (const int*)d_in[3];
    const int*   imw     = (const int*)d_in[4];
    float* out = (float*)d_out;

    char* ws = (char*)d_ws;
    float* boxes_ws = (float*)ws;                                  // 512000 B
    float* prob_ws  = (float*)(ws + 512000);                       // 128000 B
    unsigned long long* valid_ws = (unsigned long long*)(ws + 640000);  // 4096 B
    unsigned long long* mask_ws  = (unsigned long long*)(ws + 644096);  // 4096000 B

    select_decode_kernel<<<BATCH, 1024, 0, stream>>>(obj, deltas, anchors, imh, imw,
                                                     boxes_ws, prob_ws, valid_ws);
    mask_kernel<<<BATCH * 8, 1024, 0, stream>>>(boxes_ws, mask_ws);
    nms_out_kernel<<<BATCH, 256, 0, stream>>>(boxes_ws, prob_ws, valid_ws, mask_ws, out);
}

// Round 2
// 430.387 us; speedup vs baseline: 1.3552x; 1.3552x over previous
//
#include <hip/hip_runtime.h>
#include <math.h>

#define BATCH 32
#define A_PER 9
#define FH 100
#define FW 100
#define A_TOT (FH*FW*A_PER)   /* 90000 */
#define KSEL 1000
#define BUFCAP 2048
#define NMS_T 0.7f
#define MIN_SZ 0.001f
#define BBOX_CLIP_F 4.135166556742356f

__device__ __forceinline__ unsigned int f2key(float f) {
    unsigned int u = __float_as_uint(f);
    return u ^ ((u & 0x80000000u) ? 0xFFFFFFFFu : 0x80000000u);
}
__device__ __forceinline__ float key2f(unsigned int k) {
    return __uint_as_float((k & 0x80000000u) ? (k ^ 0x80000000u) : ~k);
}

// ---------------- Kernel 1: exact top-1000 select + sort + decode ----------
__global__ __launch_bounds__(1024) void select_decode_kernel(
    const float* __restrict__ obj,      // [B,9,100,100]
    const float* __restrict__ deltas,   // [B,36,100,100]
    const float* __restrict__ anchors,  // [90000,4]
    const int* __restrict__ imh_p, const int* __restrict__ imw_p,
    float* __restrict__ boxes_ws, float* __restrict__ prob_ws,
    unsigned long long* __restrict__ valid_ws)
{
    const int b = blockIdx.x;
    const int tid = threadIdx.x;
    const int lane = tid & 63;
    const float* sc = obj + (size_t)b * A_TOT;

    __shared__ unsigned int hist[256];
    __shared__ unsigned int sh_prefix, sh_want, sh_cnt;
    __shared__ unsigned long long buf[BUFCAP];
    __shared__ unsigned long long vbits[16];

    if (tid == 0) { sh_prefix = 0u; sh_want = KSEL; sh_cnt = 0u; }

    // ---- radix select over top 24 bits: wave-aggregated histogram ----
    for (int p = 0; p < 3; ++p) {
        for (int i = tid; i < 256; i += 1024) hist[i] = 0u;
        __syncthreads();
        unsigned int prefix = sh_prefix;
        unsigned int want = sh_want;
        int shift = 24 - 8 * p;
        for (int e = tid; e < A_TOT; e += 1024) {
            unsigned int key = f2key(sc[e]);
            bool ok = (p == 0) ? true : ((key >> (shift + 8)) == prefix);
            unsigned int bin = (key >> shift) & 255u;
            unsigned long long act = __ballot(ok ? 1 : 0);
            unsigned long long m = act;
#pragma unroll
            for (int bit = 0; bit < 8; ++bit) {
                unsigned long long v = __ballot((ok && ((bin >> bit) & 1u)) ? 1 : 0);
                m &= ((bin >> bit) & 1u) ? v : ~v;
            }
            if (ok) {
                int leader = __ffsll(m) - 1;
                if (lane == leader) atomicAdd(&hist[bin], (unsigned int)__popcll(m));
            }
        }
        __syncthreads();
        // parallel find of threshold bin: wave 0, lane l covers bins 4l..4l+3
        if (tid < 64) {
            unsigned int h0 = hist[4*tid+0], h1 = hist[4*tid+1];
            unsigned int h2 = hist[4*tid+2], h3 = hist[4*tid+3];
            unsigned int ls = h0 + h1 + h2 + h3;
            unsigned int x = ls;
#pragma unroll
            for (int off = 1; off < 64; off <<= 1) {
                unsigned int v = __shfl_down(x, off);
                if (tid + off < 64) x += v;
            }
            unsigned int a3 = x - ls;      // sum of all bins in lanes > tid
            unsigned int a2 = a3 + h3;
            unsigned int a1 = a2 + h2;
            unsigned int a0 = a1 + h1;
            if (a3 < want && want <= a3 + h3) { sh_prefix = (prefix<<8)|(4u*(unsigned)tid+3u); sh_want = want - a3; }
            if (a2 < want && want <= a2 + h2) { sh_prefix = (prefix<<8)|(4u*(unsigned)tid+2u); sh_want = want - a2; }
            if (a1 < want && want <= a1 + h1) { sh_prefix = (prefix<<8)|(4u*(unsigned)tid+1u); sh_want = want - a1; }
            if (a0 < want && want <= a0 + h0) { sh_prefix = (prefix<<8)|(4u*(unsigned)tid+0u); sh_want = want - a0; }
        }
        __syncthreads();
    }
    unsigned int T = sh_prefix;   // 24-bit prefix containing rank-1000 key

    // ---- gather all elements with key>>8 >= T (composite 64-bit keys) ----
    for (int e = tid; e < A_TOT; e += 1024) {
        unsigned int key = f2key(sc[e]);
        if ((key >> 8) >= T) {
            unsigned int pos = atomicAdd(&sh_cnt, 1u);
            if (pos < BUFCAP) {
                int a = e / 10000; int rem = e - a * 10000;   // rem = h*100+w
                unsigned int i = (unsigned int)(rem * 9 + a); // flat (h,w,a) index
                buf[pos] = ((unsigned long long)key << 32) | (unsigned int)(~i);
            }
        }
    }
    __syncthreads();
    unsigned int cnt = sh_cnt; if (cnt > BUFCAP) cnt = BUFCAP;
    int n = (cnt <= 1024u) ? 1024 : BUFCAP;
    for (int i = tid; i < BUFCAP; i += 1024) if (i >= (int)cnt) buf[i] = 0ull;

    // ---- bitonic sort descending (score desc, index asc on ties) ----
    for (int k2 = 2; k2 <= n; k2 <<= 1) {
        for (int j = k2 >> 1; j > 0; j >>= 1) {
            __syncthreads();
            for (int idx = tid; idx < n; idx += 1024) {
                int ixj = idx ^ j;
                if (ixj > idx) {
                    unsigned long long x = buf[idx], y = buf[ixj];
                    if (((idx & k2) == 0) ? (x < y) : (x > y)) {
                        buf[idx] = y; buf[ixj] = x;
                    }
                }
            }
        }
    }
    if (tid < 16) vbits[tid] = 0ull;
    __syncthreads();

    // ---- decode + clip + valid for the 1000 winners ----
    float imw = (float)(*imw_p);
    float imh = (float)(*imh_p);
    if (tid < KSEL) {
        int r = tid;
        unsigned long long kv = buf[r];
        unsigned int keyhi = (unsigned int)(kv >> 32);
        unsigned int i = ~((unsigned int)kv);
        float score = key2f(keyhi);
        float prob = 1.0f / (1.0f + expf(-score));

        int a = (int)(i % 9u); int hw = (int)(i / 9u);
        int h = hw / 100, w = hw - 100 * (hw / 100);
        const float* D = deltas + (size_t)b * 36 * 10000;
        int off = h * 100 + w;
        float dx  = D[(a * 4 + 0) * 10000 + off];
        float dy  = D[(a * 4 + 1) * 10000 + off];
        float dwv = fminf(D[(a * 4 + 2) * 10000 + off], BBOX_CLIP_F);
        float dhv = fminf(D[(a * 4 + 3) * 10000 + off], BBOX_CLIP_F);
        const float* anc = anchors + (size_t)i * 4;
        float ax1 = anc[0], ay1 = anc[1], ax2 = anc[2], ay2 = anc[3];
        float aw = ax2 - ax1, ah = ay2 - ay1;
        float acx = ax1 + 0.5f * aw, acy = ay1 + 0.5f * ah;
        float pcx = dx * aw + acx, pcy = dy * ah + acy;
        float pw = expf(dwv) * aw, ph = expf(dhv) * ah;
        float x1 = pcx - 0.5f * pw, y1 = pcy - 0.5f * ph;
        float x2 = pcx + 0.5f * pw, y2 = pcy + 0.5f * ph;
        x1 = fminf(fmaxf(x1, 0.0f), imw);
        y1 = fminf(fmaxf(y1, 0.0f), imh);
        x2 = fminf(fmaxf(x2, 0.0f), imw);
        y2 = fminf(fmaxf(y2, 0.0f), imh);
        bool valid = ((x2 - x1) >= MIN_SZ) && ((y2 - y1) >= MIN_SZ) && (prob >= 0.0f);
        size_t bo = ((size_t)b * KSEL + r) * 4;
        boxes_ws[bo + 0] = x1; boxes_ws[bo + 1] = y1;
        boxes_ws[bo + 2] = x2; boxes_ws[bo + 3] = y2;
        prob_ws[(size_t)b * KSEL + r] = prob;
        if (valid) atomicOr(&vbits[r >> 6], 1ull << (r & 63));
    }
    __syncthreads();
    if (tid < 16) valid_ws[b * 16 + tid] = vbits[tid];
}

// ---------------- Kernel 2: 1000x1000 suppression bitmatrix ----------------
__global__ __launch_bounds__(1024) void mask_kernel(
    const float* __restrict__ boxes_ws, unsigned long long* __restrict__ mask_ws)
{
    const int b = blockIdx.x >> 3;
    const int part = blockIdx.x & 7;
    const int tid = threadIdx.x;
    const int lane = tid & 63;
    const int wv = tid >> 6;          // 0..15
    __shared__ float4 bx[KSEL];
    __shared__ float ar[KSEL];
    for (int r = tid; r < KSEL; r += 1024) {
        float4 v = ((const float4*)boxes_ws)[(size_t)b * KSEL + r];
        bx[r] = v;
        ar[r] = (v.z - v.x) * (v.w - v.y);
    }
    __syncthreads();
    int slot = part * 16 + wv;        // 0..127
    for (int r = slot; r < KSEL; r += 128) {
        float4 a = bx[r];
        float area_a = ar[r];
        unsigned long long* row = mask_ws + ((size_t)b * KSEL + r) * 16;
        int wlo = r >> 6;
        for (int t = 0; t < 16; ++t) {
            if (t < wlo) { if (lane == 0) row[t] = 0ull; continue; }
            int j = (t << 6) | lane;
            bool bit = false;
            if (j > r && j < KSEL) {
                float4 c = bx[j];
                float xx1 = fmaxf(a.x, c.x), yy1 = fmaxf(a.y, c.y);
                float xx2 = fminf(a.z, c.z), yy2 = fminf(a.w, c.w);
                float iw = fmaxf(xx2 - xx1, 0.0f), ih = fmaxf(yy2 - yy1, 0.0f);
                float inter = iw * ih;
                float iou = inter / (area_a + ar[j] - inter + 1e-12f);
                bit = iou > NMS_T;
            }
            unsigned long long m = __ballot(bit ? 1 : 0);
            if (lane == 0) row[t] = m;
        }
    }
}

// ---------------- Kernel 3: greedy chain (kept-bits only) + compaction -----
__global__ __launch_bounds__(256) void nms_out_kernel(
    const float* __restrict__ boxes_ws, const float* __restrict__ prob_ws,
    const unsigned long long* __restrict__ valid_ws,
    const unsigned long long* __restrict__ mask_ws,
    float* __restrict__ out)
{
    const int b = blockIdx.x;
    const int tid = threadIdx.x;
    const int lane = tid & 63;
    __shared__ unsigned long long keep_lds[16];
    __shared__ unsigned int psum[16];
    __shared__ int klist[KSEL];

    if (tid < 64) {
        const unsigned long long* M = mask_ws + (size_t)b * KSEL * 16;
        // diagonal 64x64 blocks: Dd[w] on lane j = suppression word w of row w*64+j
        unsigned long long Dd[16];
#pragma unroll
        for (int w = 0; w < 16; ++w) {
            int row = w * 64 + lane;
            Dd[w] = (row < KSEL) ? M[(size_t)row * 16 + w] : 0ull;
        }
        unsigned long long validw = (lane < 16) ? valid_ws[b * 16 + lane] : 0ull;
        int cnt = 0;    // uniform across lanes
#pragma unroll
        for (int w = 0; w < 16; ++w) {
            // suppression of word w by all kept boxes in earlier words:
            // batched gather (issue all loads, single wait) + OR-reduce
            unsigned long long g[16];
            int nr = (cnt + 63) >> 6;
#pragma unroll
            for (int rnd = 0; rnd < 16; ++rnd) {
                g[rnd] = 0ull;
                if (rnd < nr) {
                    int j = rnd * 64 + lane;
                    if (j < cnt) g[rnd] = M[(size_t)klist[j] * 16 + w];
                }
            }
            unsigned long long sup = 0ull;
#pragma unroll
            for (int rnd = 0; rnd < 16; ++rnd) sup |= g[rnd];
#pragma unroll
            for (int off = 32; off > 0; off >>= 1)
                sup |= __shfl_xor(sup, off);

            unsigned long long cw = __shfl(validw, w) & ~sup;
            unsigned long long Dw = Dd[w];
            unsigned long long keptw = 0ull;
            while (cw) {                         // iterates KEPT bits only
                int p = __ffsll(cw) - 1;
                keptw |= (1ull << p);
                if (lane == 0) klist[cnt] = w * 64 + p;
                cnt++;
                unsigned long long dp = __shfl(Dw, p);   // on-chain: one shfl
                unsigned long long above = (p < 63) ? ((~0ull) << (p + 1)) : 0ull;
                cw &= above & ~dp;
            }
            if (lane == 0) keep_lds[w] = keptw;
        }
    }
    __syncthreads();
    if (tid == 0) {
        unsigned int s = 0;
        for (int wq = 0; wq < 16; ++wq) { psum[wq] = s; s += __popcll(keep_lds[wq]); }
    }
    __syncthreads();

    float* ob = out;                                     // [B,1000,4]
    float* op = out + (size_t)BATCH * KSEL * 4;          // [B,1000]
    float* om = op + (size_t)BATCH * KSEL;               // [B,1000]
    float* obb = ob + (size_t)b * KSEL * 4;
    float* opb = op + (size_t)b * KSEL;
    float* omb = om + (size_t)b * KSEL;

    for (int r = tid; r < KSEL; r += 256) {
        obb[r * 4 + 0] = 0.0f; obb[r * 4 + 1] = 0.0f;
        obb[r * 4 + 2] = 0.0f; obb[r * 4 + 3] = 0.0f;
        opb[r] = 0.0f; omb[r] = 0.0f;
    }
    __syncthreads();
    for (int r = tid; r < KSEL; r += 256) {
        unsigned long long kw = keep_lds[r >> 6];
        if ((kw >> (r & 63)) & 1ull) {
            unsigned int p = psum[r >> 6] + (unsigned int)__popcll(kw & ((1ull << (r & 63)) - 1ull));
            size_t src = ((size_t)b * KSEL + r) * 4;
            obb[p * 4 + 0] = boxes_ws[src + 0];
            obb[p * 4 + 1] = boxes_ws[src + 1];
            obb[p * 4 + 2] = boxes_ws[src + 2];
            obb[p * 4 + 3] = boxes_ws[src + 3];
            opb[p] = prob_ws[(size_t)b * KSEL + r];
            omb[p] = 1.0f;
        }
    }
}

extern "C" void kernel_launch(void* const* d_in, const int* in_sizes, int n_in,
                              void* d_out, int out_size, void* d_ws, size_t ws_size,
                              hipStream_t stream) {
    const float* obj     = (const float*)d_in[0];
    const float* deltas  = (const float*)d_in[1];
    const float* anchors = (const float*)d_in[2];
    const int*   imh     = (const int*)d_in[3];
    const int*   imw     = (const int*)d_in[4];
    float* out = (float*)d_out;

    char* ws = (char*)d_ws;
    float* boxes_ws = (float*)ws;                                  // 512000 B
    float* prob_ws  = (float*)(ws + 512000);                       // 128000 B
    unsigned long long* valid_ws = (unsigned long long*)(ws + 640000);  // 4096 B
    unsigned long long* mask_ws  = (unsigned long long*)(ws + 644096);  // 4096000 B

    select_decode_kernel<<<BATCH, 1024, 0, stream>>>(obj, deltas, anchors, imh, imw,
                                                     boxes_ws, prob_ws, valid_ws);
    mask_kernel<<<BATCH * 8, 1024, 0, stream>>>(boxes_ws, mask_ws);
    nms_out_kernel<<<BATCH, 256, 0, stream>>>(boxes_ws, prob_ws, valid_ws, mask_ws, out);
}

// Round 3
// 204.016 us; speedup vs baseline: 2.8588x; 2.1096x over previous
//
#include <hip/hip_runtime.h>
#include <math.h>

#define BATCH 32
#define A_PER 9
#define FH 100
#define FW 100
#define A_TOT (FH*FW*A_PER)   /* 90000 */
#define KSEL 1000
#define BUFCAP 2048
#define NBIN 4096             /* 12-bit prefix histogram */
#define NMS_T 0.7f
#define MIN_SZ 0.001f
#define BBOX_CLIP_F 4.135166556742356f

__device__ __forceinline__ unsigned int f2key(float f) {
    unsigned int u = __float_as_uint(f);
    return u ^ ((u & 0x80000000u) ? 0xFFFFFFFFu : 0x80000000u);
}
__device__ __forceinline__ float key2f(unsigned int k) {
    return __uint_as_float((k & 0x80000000u) ? (k ^ 0x80000000u) : ~k);
}

// ---------------- Kernel 0: zero the global histogram -----------------------
__global__ __launch_bounds__(256) void zero_hist_kernel(uint4* __restrict__ g)
{
    g[blockIdx.x * 256 + threadIdx.x] = make_uint4(0u, 0u, 0u, 0u);
}

// ---------------- Kernel 1: per-image 4096-bin histogram (8 blocks/image) ---
__global__ __launch_bounds__(256) void hist_kernel(
    const float* __restrict__ obj, unsigned int* __restrict__ ghist)
{
    const int b = blockIdx.x >> 3;
    const int part = blockIdx.x & 7;
    const int tid = threadIdx.x;
    __shared__ unsigned int h[NBIN];
    for (int i = tid; i < NBIN; i += 256) h[i] = 0u;
    __syncthreads();
    const float4* sc4 = (const float4*)(obj + (size_t)b * A_TOT);
    for (int i = part * 256 + tid; i < A_TOT / 4; i += 2048) {
        float4 v = sc4[i];
        atomicAdd(&h[f2key(v.x) >> 20], 1u);
        atomicAdd(&h[f2key(v.y) >> 20], 1u);
        atomicAdd(&h[f2key(v.z) >> 20], 1u);
        atomicAdd(&h[f2key(v.w) >> 20], 1u);
    }
    __syncthreads();
    unsigned int* gh = ghist + (size_t)b * NBIN;
    for (int i = tid; i < NBIN; i += 256)
        if (h[i]) atomicAdd(&gh[i], h[i]);
}

// ---------------- Kernel 2: threshold scan + gather + sort + decode ---------
__global__ __launch_bounds__(1024) void select_decode_kernel(
    const float* __restrict__ obj,
    const float* __restrict__ deltas,
    const float* __restrict__ anchors,
    const int* __restrict__ imh_p, const int* __restrict__ imw_p,
    const unsigned int* __restrict__ ghist,
    float* __restrict__ boxes_ws, float* __restrict__ prob_ws,
    unsigned long long* __restrict__ valid_ws)
{
    const int b = blockIdx.x;
    const int tid = threadIdx.x;
    const int lane = tid & 63;
    const int wv = tid >> 6;

    __shared__ unsigned int wsum[16];
    __shared__ unsigned int sh_T, sh_cnt;
    __shared__ unsigned long long buf[BUFCAP];
    __shared__ unsigned long long vbits[16];

    if (tid == 0) sh_cnt = 0u;

    // ---- find threshold bin T: largest bin with suffix-count crossing 1000 ----
    const unsigned int* gh = ghist + (size_t)b * NBIN;
    unsigned int h0 = gh[tid * 4 + 0], h1 = gh[tid * 4 + 1];
    unsigned int h2 = gh[tid * 4 + 2], h3 = gh[tid * 4 + 3];
    unsigned int ts = h0 + h1 + h2 + h3;
    unsigned int x = ts;
#pragma unroll
    for (int off = 1; off < 64; off <<= 1) {
        unsigned int v = __shfl_down(x, off);
        if (lane + off < 64) x += v;
    }
    if (lane == 0) wsum[wv] = x;     // per-wave total
    __syncthreads();
    unsigned int swave = 0;
    for (int q = wv + 1; q < 16; ++q) swave += wsum[q];
    unsigned int S_hi = swave + (x - ts);        // count in bins above this thread
    unsigned int a3 = S_hi;
    unsigned int a2 = a3 + h3;
    unsigned int a1 = a2 + h2;
    unsigned int a0 = a1 + h1;
    if (a3 < KSEL && a3 + h3 >= KSEL) sh_T = (unsigned)(tid * 4 + 3);
    if (a2 < KSEL && a2 + h2 >= KSEL) sh_T = (unsigned)(tid * 4 + 2);
    if (a1 < KSEL && a1 + h1 >= KSEL) sh_T = (unsigned)(tid * 4 + 1);
    if (a0 < KSEL && a0 + h0 >= KSEL) sh_T = (unsigned)(tid * 4 + 0);
    __syncthreads();
    unsigned int T = sh_T;

    // ---- gather all elements with 12-bit prefix >= T (composite keys) ----
    const float4* sc4 = (const float4*)(obj + (size_t)b * A_TOT);
    for (int i4 = tid; i4 < A_TOT / 4; i4 += 1024) {
        float4 v = sc4[i4];
        float vs[4] = {v.x, v.y, v.z, v.w};
#pragma unroll
        for (int c = 0; c < 4; ++c) {
            unsigned int key = f2key(vs[c]);
            if ((key >> 20) >= T) {
                unsigned int pos = atomicAdd(&sh_cnt, 1u);
                if (pos < BUFCAP) {
                    int e = i4 * 4 + c;
                    int a = e / 10000; int rem = e - a * 10000;     // rem = h*100+w
                    unsigned int i = (unsigned int)(rem * 9 + a);   // flat (h,w,a)
                    buf[pos] = ((unsigned long long)key << 32) | (unsigned int)(~i);
                }
            }
        }
    }
    __syncthreads();
    unsigned int cnt = sh_cnt; if (cnt > BUFCAP) cnt = BUFCAP;
    int n = (cnt <= 1024u) ? 1024 : BUFCAP;
    for (int i = tid; i < BUFCAP; i += 1024) if (i >= (int)cnt) buf[i] = 0ull;

    // ---- bitonic sort descending (score desc, index asc on ties) ----
    for (int k2 = 2; k2 <= n; k2 <<= 1) {
        for (int j = k2 >> 1; j > 0; j >>= 1) {
            __syncthreads();
            for (int idx = tid; idx < n; idx += 1024) {
                int ixj = idx ^ j;
                if (ixj > idx) {
                    unsigned long long xx = buf[idx], yy = buf[ixj];
                    if (((idx & k2) == 0) ? (xx < yy) : (xx > yy)) {
                        buf[idx] = yy; buf[ixj] = xx;
                    }
                }
            }
        }
    }
    if (tid < 16) vbits[tid] = 0ull;
    __syncthreads();

    // ---- decode + clip + valid for the 1000 winners ----
    float imw = (float)(*imw_p);
    float imh = (float)(*imh_p);
    if (tid < KSEL) {
        int r = tid;
        unsigned long long kv = buf[r];
        unsigned int keyhi = (unsigned int)(kv >> 32);
        unsigned int i = ~((unsigned int)kv);
        float score = key2f(keyhi);
        float prob = 1.0f / (1.0f + expf(-score));

        int a = (int)(i % 9u); int hw = (int)(i / 9u);
        int h = hw / 100, w = hw - 100 * (hw / 100);
        const float* D = deltas + (size_t)b * 36 * 10000;
        int off = h * 100 + w;
        float dx  = D[(a * 4 + 0) * 10000 + off];
        float dy  = D[(a * 4 + 1) * 10000 + off];
        float dwv = fminf(D[(a * 4 + 2) * 10000 + off], BBOX_CLIP_F);
        float dhv = fminf(D[(a * 4 + 3) * 10000 + off], BBOX_CLIP_F);
        const float* anc = anchors + (size_t)i * 4;
        float ax1 = anc[0], ay1 = anc[1], ax2 = anc[2], ay2 = anc[3];
        float aw = ax2 - ax1, ah = ay2 - ay1;
        float acx = ax1 + 0.5f * aw, acy = ay1 + 0.5f * ah;
        float pcx = dx * aw + acx, pcy = dy * ah + acy;
        float pw = expf(dwv) * aw, ph = expf(dhv) * ah;
        float x1 = pcx - 0.5f * pw, y1 = pcy - 0.5f * ph;
        float x2 = pcx + 0.5f * pw, y2 = pcy + 0.5f * ph;
        x1 = fminf(fmaxf(x1, 0.0f), imw);
        y1 = fminf(fmaxf(y1, 0.0f), imh);
        x2 = fminf(fmaxf(x2, 0.0f), imw);
        y2 = fminf(fmaxf(y2, 0.0f), imh);
        bool valid = ((x2 - x1) >= MIN_SZ) && ((y2 - y1) >= MIN_SZ) && (prob >= 0.0f);
        size_t bo = ((size_t)b * KSEL + r) * 4;
        boxes_ws[bo + 0] = x1; boxes_ws[bo + 1] = y1;
        boxes_ws[bo + 2] = x2; boxes_ws[bo + 3] = y2;
        prob_ws[(size_t)b * KSEL + r] = prob;
        if (valid) atomicOr(&vbits[r >> 6], 1ull << (r & 63));
    }
    __syncthreads();
    if (tid < 16) valid_ws[b * 16 + tid] = vbits[tid];
}

// ---------------- Kernel 3: 1000x1000 suppression bitmatrix ----------------
__global__ __launch_bounds__(1024) void mask_kernel(
    const float* __restrict__ boxes_ws, unsigned long long* __restrict__ mask_ws)
{
    const int b = blockIdx.x >> 3;
    const int part = blockIdx.x & 7;
    const int tid = threadIdx.x;
    const int lane = tid & 63;
    const int wv = tid >> 6;          // 0..15
    __shared__ float4 bx[KSEL];
    __shared__ float ar[KSEL];
    for (int r = tid; r < KSEL; r += 1024) {
        float4 v = ((const float4*)boxes_ws)[(size_t)b * KSEL + r];
        bx[r] = v;
        ar[r] = (v.z - v.x) * (v.w - v.y);
    }
    __syncthreads();
    int slot = part * 16 + wv;        // 0..127
    for (int r = slot; r < KSEL; r += 128) {
        float4 a = bx[r];
        float area_a = ar[r];
        unsigned long long* row = mask_ws + ((size_t)b * KSEL + r) * 16;
        int wlo = r >> 6;
        for (int t = 0; t < 16; ++t) {
            if (t < wlo) { if (lane == 0) row[t] = 0ull; continue; }
            int j = (t << 6) | lane;
            bool bit = false;
            if (j > r && j < KSEL) {
                float4 c = bx[j];
                float xx1 = fmaxf(a.x, c.x), yy1 = fmaxf(a.y, c.y);
                float xx2 = fminf(a.z, c.z), yy2 = fminf(a.w, c.w);
                float iw = fmaxf(xx2 - xx1, 0.0f), ih = fmaxf(yy2 - yy1, 0.0f);
                float inter = iw * ih;
                float iou = inter / (area_a + ar[j] - inter + 1e-12f);
                bit = iou > NMS_T;
            }
            unsigned long long m = __ballot(bit ? 1 : 0);
            if (lane == 0) row[t] = m;
        }
    }
}

// ------- Kernel 4: greedy NMS (conflict fast-path) + stable compaction -----
__global__ __launch_bounds__(1024) void nms_out_kernel(
    const float* __restrict__ boxes_ws, const float* __restrict__ prob_ws,
    const unsigned long long* __restrict__ valid_ws,
    const unsigned long long* __restrict__ mask_ws,
    float* __restrict__ out)
{
    const int b = blockIdx.x;
    const int tid = threadIdx.x;
    const int lane = tid & 63;
    const int wv = tid >> 6;

    __shared__ unsigned long long partial[16];
    __shared__ unsigned long long keepw_sh[16];
    __shared__ unsigned int psum[16];
    __shared__ int klist[1024];
    __shared__ int cnt_sh;

    const unsigned long long* M = mask_ws + (size_t)b * KSEL * 16;

    // wave 0: diagonal 64x64 blocks + validity words in registers
    unsigned long long Dd[16];
    unsigned long long validw = 0ull;
    if (wv == 0) {
#pragma unroll
        for (int w = 0; w < 16; ++w) {
            int row = w * 64 + lane;
            Dd[w] = (row < KSEL) ? M[(size_t)row * 16 + w] : 0ull;
        }
        validw = (lane < 16) ? valid_ws[b * 16 + lane] : 0ull;
    }
    if (tid == 0) { cnt_sh = 0; klist[0] = 0; }
    __syncthreads();

#pragma unroll
    for (int w = 0; w < 16; ++w) {
        // --- cooperative cross-word suppression gather: wave wv does batch wv ---
        int cnt = cnt_sh;
        int j = wv * 64 + lane;
        int jj = (j < cnt) ? j : 0;
        int kidx = klist[jj];
        unsigned long long v = M[(size_t)kidx * 16 + w];
        if (j >= cnt) v = 0ull;
#pragma unroll
        for (int off = 32; off > 0; off >>= 1) v |= __shfl_xor(v, off);
        if (lane == 0) partial[wv] = v;
        __syncthreads();

        if (wv == 0) {
            unsigned long long sup = (lane < 16) ? partial[lane] : 0ull;
#pragma unroll
            for (int off = 32; off > 0; off >>= 1) sup |= __shfl_xor(sup, off);
            unsigned long long cw = __shfl(validw, w) & ~sup;
            unsigned long long Dw = Dd[w];
            unsigned long long keptw = 0ull;
            while (cw) {
                unsigned long long myrow = Dw & cw;   // who I'd suppress among candidates
                unsigned long long confl =
                    __ballot((((cw >> lane) & 1ull) && myrow != 0ull) ? 1 : 0);
                if (confl == 0ull) { keptw |= cw; break; }     // fast path: keep all
                int c = __ffsll((long long)confl) - 1;
                unsigned long long le = (c == 63) ? ~0ull : ((1ull << (c + 1)) - 1ull);
                keptw |= cw & le;                     // all candidates <= c kept
                unsigned long long Dc = __shfl(Dw, c);
                cw &= ~le & ~Dc;                      // drop suppressed, continue above c
            }
            // append kept indices to klist (parallel rank write)
            if ((keptw >> lane) & 1ull) {
                int rank = (int)__popcll(keptw & ((1ull << lane) - 1ull));
                klist[cnt + rank] = w * 64 + lane;
            }
            if (lane == 0) {
                keepw_sh[w] = keptw;
                cnt_sh = cnt + (int)__popcll(keptw);
            }
        }
        __syncthreads();
    }

    if (tid == 0) {
        unsigned int s = 0;
        for (int wq = 0; wq < 16; ++wq) { psum[wq] = s; s += __popcll(keepw_sh[wq]); }
    }
    __syncthreads();

    float* ob = out;                                     // [B,1000,4]
    float* op = out + (size_t)BATCH * KSEL * 4;          // [B,1000]
    float* om = op + (size_t)BATCH * KSEL;               // [B,1000]
    float* obb = ob + (size_t)b * KSEL * 4;
    float* opb = op + (size_t)b * KSEL;
    float* omb = om + (size_t)b * KSEL;

    for (int r = tid; r < KSEL; r += 1024) {
        obb[r * 4 + 0] = 0.0f; obb[r * 4 + 1] = 0.0f;
        obb[r * 4 + 2] = 0.0f; obb[r * 4 + 3] = 0.0f;
        opb[r] = 0.0f; omb[r] = 0.0f;
    }
    __syncthreads();
    for (int r = tid; r < KSEL; r += 1024) {
        unsigned long long kw = keepw_sh[r >> 6];
        if ((kw >> (r & 63)) & 1ull) {
            unsigned int p = psum[r >> 6] + (unsigned int)__popcll(kw & ((1ull << (r & 63)) - 1ull));
            size_t src = ((size_t)b * KSEL + r) * 4;
            obb[p * 4 + 0] = boxes_ws[src + 0];
            obb[p * 4 + 1] = boxes_ws[src + 1];
            obb[p * 4 + 2] = boxes_ws[src + 2];
            obb[p * 4 + 3] = boxes_ws[src + 3];
            opb[p] = prob_ws[(size_t)b * KSEL + r];
            omb[p] = 1.0f;
        }
    }
}

extern "C" void kernel_launch(void* const* d_in, const int* in_sizes, int n_in,
                              void* d_out, int out_size, void* d_ws, size_t ws_size,
                              hipStream_t stream) {
    const float* obj     = (const float*)d_in[0];
    const float* deltas  = (const float*)d_in[1];
    const float* anchors = (const float*)d_in[2];
    const int*   imh     = (const int*)d_in[3];
    const int*   imw     = (const int*)d_in[4];
    float* out = (float*)d_out;

    char* ws = (char*)d_ws;
    float* boxes_ws = (float*)ws;                                       // 512000 B
    float* prob_ws  = (float*)(ws + 512000);                            // 128000 B
    unsigned long long* valid_ws = (unsigned long long*)(ws + 640000);  // 4096 B
    unsigned long long* mask_ws  = (unsigned long long*)(ws + 644096);  // 4096000 B
    // ghist (512 KB) overlays the mask region: consumed before mask_kernel runs
    unsigned int* ghist = (unsigned int*)(ws + 644096);                 // 4096*32*4 B

    zero_hist_kernel<<<BATCH * NBIN / 1024, 256, 0, stream>>>((uint4*)ghist);
    hist_kernel<<<BATCH * 8, 256, 0, stream>>>(obj, ghist);
    select_decode_kernel<<<BATCH, 1024, 0, stream>>>(obj, deltas, anchors, imh, imw,
                                                     ghist, boxes_ws, prob_ws, valid_ws);
    mask_kernel<<<BATCH * 8, 1024, 0, stream>>>(boxes_ws, mask_ws);
    nms_out_kernel<<<BATCH, 1024, 0, stream>>>(boxes_ws, prob_ws, valid_ws, mask_ws, out);
}

// Round 4
// 194.146 us; speedup vs baseline: 3.0041x; 1.0508x over previous
//
#include <hip/hip_runtime.h>
#include <math.h>

#define BATCH 32
#define A_PER 9
#define FH 100
#define FW 100
#define A_TOT (FH*FW*A_PER)   /* 90000 */
#define KSEL 1000
#define BUFCAP 2048
#define NBIN 4096             /* 12-bit prefix histogram */
#define NMS_T 0.7f
#define MIN_SZ 0.001f
#define BBOX_CLIP_F 4.135166556742356f

__device__ __forceinline__ unsigned int f2key(float f) {
    unsigned int u = __float_as_uint(f);
    return u ^ ((u & 0x80000000u) ? 0xFFFFFFFFu : 0x80000000u);
}
__device__ __forceinline__ float key2f(unsigned int k) {
    return __uint_as_float((k & 0x80000000u) ? (k ^ 0x80000000u) : ~k);
}

// ---------------- Kernel 0: zero ghist + candidate counters -----------------
__global__ __launch_bounds__(256) void zero_kernel(
    uint4* __restrict__ ghist4, uint4* __restrict__ gcnt4)
{
    if (blockIdx.x < 128) {
        ghist4[blockIdx.x * 256 + threadIdx.x] = make_uint4(0u, 0u, 0u, 0u);
    } else if (threadIdx.x < 8) {
        gcnt4[threadIdx.x] = make_uint4(0u, 0u, 0u, 0u);
    }
}

// ---------------- Kernel 1: per-image 4096-bin histogram (16 blocks/image) --
__global__ __launch_bounds__(256) void hist_kernel(
    const float* __restrict__ obj, unsigned int* __restrict__ ghist)
{
    const int b = blockIdx.x >> 4;
    const int part = blockIdx.x & 15;
    const int tid = threadIdx.x;
    __shared__ unsigned int h[NBIN];
    for (int i = tid; i < NBIN; i += 256) h[i] = 0u;
    __syncthreads();
    const float4* sc4 = (const float4*)(obj + (size_t)b * A_TOT);
    for (int i = part * 256 + tid; i < A_TOT / 4; i += 4096) {
        float4 v = sc4[i];
        atomicAdd(&h[f2key(v.x) >> 20], 1u);
        atomicAdd(&h[f2key(v.y) >> 20], 1u);
        atomicAdd(&h[f2key(v.z) >> 20], 1u);
        atomicAdd(&h[f2key(v.w) >> 20], 1u);
    }
    __syncthreads();
    unsigned int* gh = ghist + (size_t)b * NBIN;
    for (int i = tid; i < NBIN; i += 256)
        if (h[i]) atomicAdd(&gh[i], h[i]);
}

// ---------------- Kernel 2: threshold scan + distributed gather -------------
__global__ __launch_bounds__(1024) void gather_kernel(
    const float* __restrict__ obj, const unsigned int* __restrict__ ghist,
    unsigned long long* __restrict__ gcand, unsigned int* __restrict__ gcnt)
{
    const int b = blockIdx.x >> 3;
    const int part = blockIdx.x & 7;
    const int tid = threadIdx.x;
    const int lane = tid & 63;
    const int wv = tid >> 6;

    __shared__ unsigned int wsum[16];
    __shared__ unsigned int sh_T, lcnt, base_sh;
    __shared__ unsigned long long cbuf[BUFCAP];

    if (tid == 0) lcnt = 0u;

    // ---- threshold bin T: largest bin with suffix-count crossing 1000 ----
    const unsigned int* gh = ghist + (size_t)b * NBIN;
    unsigned int h0 = gh[tid * 4 + 0], h1 = gh[tid * 4 + 1];
    unsigned int h2 = gh[tid * 4 + 2], h3 = gh[tid * 4 + 3];
    unsigned int ts = h0 + h1 + h2 + h3;
    unsigned int x = ts;
#pragma unroll
    for (int off = 1; off < 64; off <<= 1) {
        unsigned int v = __shfl_down(x, off);
        if (lane + off < 64) x += v;
    }
    if (lane == 0) wsum[wv] = x;
    __syncthreads();
    unsigned int swave = 0;
    for (int q = wv + 1; q < 16; ++q) swave += wsum[q];
    unsigned int S_hi = swave + (x - ts);
    unsigned int a3 = S_hi;
    unsigned int a2 = a3 + h3;
    unsigned int a1 = a2 + h2;
    unsigned int a0 = a1 + h1;
    if (a3 < KSEL && a3 + h3 >= KSEL) sh_T = (unsigned)(tid * 4 + 3);
    if (a2 < KSEL && a2 + h2 >= KSEL) sh_T = (unsigned)(tid * 4 + 2);
    if (a1 < KSEL && a1 + h1 >= KSEL) sh_T = (unsigned)(tid * 4 + 1);
    if (a0 < KSEL && a0 + h0 >= KSEL) sh_T = (unsigned)(tid * 4 + 0);
    __syncthreads();
    unsigned int T = sh_T;

    // ---- scan this block's 1/8 slice, stage candidates in LDS ----
    const float4* sc4 = (const float4*)(obj + (size_t)b * A_TOT);
#pragma unroll
    for (int j = 0; j < 3; ++j) {
        int i4 = j * 8192 + part * 1024 + tid;
        if (i4 < A_TOT / 4) {
            float4 v = sc4[i4];
            float vs[4] = {v.x, v.y, v.z, v.w};
#pragma unroll
            for (int c = 0; c < 4; ++c) {
                unsigned int key = f2key(vs[c]);
                if ((key >> 20) >= T) {
                    unsigned int pos = atomicAdd(&lcnt, 1u);
                    if (pos < BUFCAP) {
                        int e = i4 * 4 + c;
                        int a = e / 10000; int rem = e - a * 10000;   // rem=h*100+w
                        unsigned int i = (unsigned int)(rem * 9 + a); // flat (h,w,a)
                        cbuf[pos] = ((unsigned long long)key << 32) | (unsigned int)(~i);
                    }
                }
            }
        }
    }
    __syncthreads();
    if (tid == 0) base_sh = atomicAdd(&gcnt[b], lcnt);
    __syncthreads();
    unsigned int base = base_sh, n = lcnt;
    for (unsigned int i = tid; i < n; i += 1024) {
        unsigned int p = base + i;
        if (p < BUFCAP) gcand[(size_t)b * BUFCAP + p] = cbuf[i];
    }
}

// ---------------- Kernel 3: sort + decode ----------------------------------
__global__ __launch_bounds__(1024) void sort_decode_kernel(
    const float* __restrict__ deltas,
    const float* __restrict__ anchors,
    const int* __restrict__ imh_p, const int* __restrict__ imw_p,
    const unsigned long long* __restrict__ gcand,
    const unsigned int* __restrict__ gcnt,
    float* __restrict__ boxes_ws, float* __restrict__ prob_ws,
    unsigned long long* __restrict__ valid_ws)
{
    const int b = blockIdx.x;
    const int tid = threadIdx.x;

    __shared__ unsigned long long buf[BUFCAP];
    __shared__ unsigned long long vbits[16];

    unsigned int cnt = gcnt[b]; if (cnt > BUFCAP) cnt = BUFCAP;
    const unsigned long long* gc = gcand + (size_t)b * BUFCAP;
    for (int i = tid; i < BUFCAP; i += 1024)
        buf[i] = (i < (int)cnt) ? gc[i] : 0ull;
    int n = (cnt <= 1024u) ? 1024 : BUFCAP;

    // ---- bitonic sort descending (score desc, index asc on ties) ----
    for (int k2 = 2; k2 <= n; k2 <<= 1) {
        for (int j = k2 >> 1; j > 0; j >>= 1) {
            __syncthreads();
            for (int idx = tid; idx < n; idx += 1024) {
                int ixj = idx ^ j;
                if (ixj > idx) {
                    unsigned long long xx = buf[idx], yy = buf[ixj];
                    if (((idx & k2) == 0) ? (xx < yy) : (xx > yy)) {
                        buf[idx] = yy; buf[ixj] = xx;
                    }
                }
            }
        }
    }
    if (tid < 16) vbits[tid] = 0ull;
    __syncthreads();

    // ---- decode + clip + valid for the 1000 winners ----
    float imw = (float)(*imw_p);
    float imh = (float)(*imh_p);
    if (tid < KSEL) {
        int r = tid;
        unsigned long long kv = buf[r];
        unsigned int keyhi = (unsigned int)(kv >> 32);
        unsigned int i = ~((unsigned int)kv);
        float score = key2f(keyhi);
        float prob = 1.0f / (1.0f + expf(-score));

        int a = (int)(i % 9u); int hw = (int)(i / 9u);
        int h = hw / 100, w = hw - 100 * (hw / 100);
        const float* D = deltas + (size_t)b * 36 * 10000;
        int off = h * 100 + w;
        float dx  = D[(a * 4 + 0) * 10000 + off];
        float dy  = D[(a * 4 + 1) * 10000 + off];
        float dwv = fminf(D[(a * 4 + 2) * 10000 + off], BBOX_CLIP_F);
        float dhv = fminf(D[(a * 4 + 3) * 10000 + off], BBOX_CLIP_F);
        const float* anc = anchors + (size_t)i * 4;
        float ax1 = anc[0], ay1 = anc[1], ax2 = anc[2], ay2 = anc[3];
        float aw = ax2 - ax1, ah = ay2 - ay1;
        float acx = ax1 + 0.5f * aw, acy = ay1 + 0.5f * ah;
        float pcx = dx * aw + acx, pcy = dy * ah + acy;
        float pw = expf(dwv) * aw, ph = expf(dhv) * ah;
        float x1 = pcx - 0.5f * pw, y1 = pcy - 0.5f * ph;
        float x2 = pcx + 0.5f * pw, y2 = pcy + 0.5f * ph;
        x1 = fminf(fmaxf(x1, 0.0f), imw);
        y1 = fminf(fmaxf(y1, 0.0f), imh);
        x2 = fminf(fmaxf(x2, 0.0f), imw);
        y2 = fminf(fmaxf(y2, 0.0f), imh);
        bool valid = ((x2 - x1) >= MIN_SZ) && ((y2 - y1) >= MIN_SZ) && (prob >= 0.0f);
        size_t bo = ((size_t)b * KSEL + r) * 4;
        boxes_ws[bo + 0] = x1; boxes_ws[bo + 1] = y1;
        boxes_ws[bo + 2] = x2; boxes_ws[bo + 3] = y2;
        prob_ws[(size_t)b * KSEL + r] = prob;
        if (valid) atomicOr(&vbits[r >> 6], 1ull << (r & 63));
    }
    __syncthreads();
    if (tid < 16) valid_ws[b * 16 + tid] = vbits[tid];
}

// ---------------- Kernel 4: 1000x1000 suppression bitmatrix ----------------
__global__ __launch_bounds__(1024) void mask_kernel(
    const float* __restrict__ boxes_ws, unsigned long long* __restrict__ mask_ws)
{
    const int b = blockIdx.x >> 3;
    const int part = blockIdx.x & 7;
    const int tid = threadIdx.x;
    const int lane = tid & 63;
    const int wv = tid >> 6;          // 0..15
    __shared__ float4 bx[KSEL];
    __shared__ float ar[KSEL];
    for (int r = tid; r < KSEL; r += 1024) {
        float4 v = ((const float4*)boxes_ws)[(size_t)b * KSEL + r];
        bx[r] = v;
        ar[r] = (v.z - v.x) * (v.w - v.y);
    }
    __syncthreads();
    int slot = part * 16 + wv;        // 0..127
    for (int r = slot; r < KSEL; r += 128) {
        float4 a = bx[r];
        float area_a = ar[r];
        unsigned long long* row = mask_ws + ((size_t)b * KSEL + r) * 16;
        int wlo = r >> 6;
        for (int t = 0; t < 16; ++t) {
            if (t < wlo) { if (lane == 0) row[t] = 0ull; continue; }
            int j = (t << 6) | lane;
            bool bit = false;
            if (j > r && j < KSEL) {
                float4 c = bx[j];
                float xx1 = fmaxf(a.x, c.x), yy1 = fmaxf(a.y, c.y);
                float xx2 = fminf(a.z, c.z), yy2 = fminf(a.w, c.w);
                float iw = fmaxf(xx2 - xx1, 0.0f), ih = fmaxf(yy2 - yy1, 0.0f);
                float inter = iw * ih;
                float iou = inter / (area_a + ar[j] - inter + 1e-12f);
                bit = iou > NMS_T;
            }
            unsigned long long m = __ballot(bit ? 1 : 0);
            if (lane == 0) row[t] = m;
        }
    }
}

// ------- Kernel 5: greedy NMS (conflict fast-path) + stable compaction -----
__global__ __launch_bounds__(1024) void nms_out_kernel(
    const float* __restrict__ boxes_ws, const float* __restrict__ prob_ws,
    const unsigned long long* __restrict__ valid_ws,
    const unsigned long long* __restrict__ mask_ws,
    float* __restrict__ out)
{
    const int b = blockIdx.x;
    const int tid = threadIdx.x;
    const int lane = tid & 63;
    const int wv = tid >> 6;

    __shared__ unsigned long long partial[16];
    __shared__ unsigned long long keepw_sh[16];
    __shared__ unsigned int psum[16];
    __shared__ int klist[1024];
    __shared__ int cnt_sh;

    const unsigned long long* M = mask_ws + (size_t)b * KSEL * 16;

    // wave 0: diagonal 64x64 blocks + validity words in registers
    unsigned long long Dd[16];
    unsigned long long validw = 0ull;
    if (wv == 0) {
#pragma unroll
        for (int w = 0; w < 16; ++w) {
            int row = w * 64 + lane;
            Dd[w] = (row < KSEL) ? M[(size_t)row * 16 + w] : 0ull;
        }
        validw = (lane < 16) ? valid_ws[b * 16 + lane] : 0ull;
    }
    if (tid == 0) { cnt_sh = 0; klist[0] = 0; }
    __syncthreads();

#pragma unroll
    for (int w = 0; w < 16; ++w) {
        // --- cooperative cross-word suppression gather: wave wv does batch wv ---
        int cnt = cnt_sh;
        int j = wv * 64 + lane;
        int jj = (j < cnt) ? j : 0;
        int kidx = klist[jj];
        unsigned long long v = M[(size_t)kidx * 16 + w];
        if (j >= cnt) v = 0ull;
#pragma unroll
        for (int off = 32; off > 0; off >>= 1) v |= __shfl_xor(v, off);
        if (lane == 0) partial[wv] = v;
        __syncthreads();

        if (wv == 0) {
            unsigned long long sup = (lane < 16) ? partial[lane] : 0ull;
#pragma unroll
            for (int off = 32; off > 0; off >>= 1) sup |= __shfl_xor(sup, off);
            unsigned long long cw = __shfl(validw, w) & ~sup;
            unsigned long long Dw = Dd[w];
            unsigned long long keptw = 0ull;
            while (cw) {
                unsigned long long myrow = Dw & cw;   // who I'd suppress among candidates
                unsigned long long confl =
                    __ballot((((cw >> lane) & 1ull) && myrow != 0ull) ? 1 : 0);
                if (confl == 0ull) { keptw |= cw; break; }     // fast path: keep all
                int c = __ffsll((long long)confl) - 1;
                unsigned long long le = (c == 63) ? ~0ull : ((1ull << (c + 1)) - 1ull);
                keptw |= cw & le;                     // all candidates <= c kept
                unsigned long long Dc = __shfl(Dw, c);
                cw &= ~le & ~Dc;                      // drop suppressed, continue above c
            }
            // append kept indices to klist (parallel rank write)
            if ((keptw >> lane) & 1ull) {
                int rank = (int)__popcll(keptw & ((1ull << lane) - 1ull));
                klist[cnt + rank] = w * 64 + lane;
            }
            if (lane == 0) {
                keepw_sh[w] = keptw;
                cnt_sh = cnt + (int)__popcll(keptw);
            }
        }
        __syncthreads();
    }

    if (tid == 0) {
        unsigned int s = 0;
        for (int wq = 0; wq < 16; ++wq) { psum[wq] = s; s += __popcll(keepw_sh[wq]); }
    }
    __syncthreads();

    float* ob = out;                                     // [B,1000,4]
    float* op = out + (size_t)BATCH * KSEL * 4;          // [B,1000]
    float* om = op + (size_t)BATCH * KSEL;               // [B,1000]
    float* obb = ob + (size_t)b * KSEL * 4;
    float* opb = op + (size_t)b * KSEL;
    float* omb = om + (size_t)b * KSEL;

    for (int r = tid; r < KSEL; r += 1024) {
        obb[r * 4 + 0] = 0.0f; obb[r * 4 + 1] = 0.0f;
        obb[r * 4 + 2] = 0.0f; obb[r * 4 + 3] = 0.0f;
        opb[r] = 0.0f; omb[r] = 0.0f;
    }
    __syncthreads();
    for (int r = tid; r < KSEL; r += 1024) {
        unsigned long long kw = keepw_sh[r >> 6];
        if ((kw >> (r & 63)) & 1ull) {
            unsigned int p = psum[r >> 6] + (unsigned int)__popcll(kw & ((1ull << (r & 63)) - 1ull));
            size_t src = ((size_t)b * KSEL + r) * 4;
            obb[p * 4 + 0] = boxes_ws[src + 0];
            obb[p * 4 + 1] = boxes_ws[src + 1];
            obb[p * 4 + 2] = boxes_ws[src + 2];
            obb[p * 4 + 3] = boxes_ws[src + 3];
            opb[p] = prob_ws[(size_t)b * KSEL + r];
            omb[p] = 1.0f;
        }
    }
}

extern "C" void kernel_launch(void* const* d_in, const int* in_sizes, int n_in,
                              void* d_out, int out_size, void* d_ws, size_t ws_size,
                              hipStream_t stream) {
    const float* obj     = (const float*)d_in[0];
    const float* deltas  = (const float*)d_in[1];
    const float* anchors = (const float*)d_in[2];
    const int*   imh     = (const int*)d_in[3];
    const int*   imw     = (const int*)d_in[4];
    float* out = (float*)d_out;

    char* ws = (char*)d_ws;
    float* boxes_ws = (float*)ws;                                       // 512000 B
    float* prob_ws  = (float*)(ws + 512000);                            // 128000 B
    unsigned long long* valid_ws = (unsigned long long*)(ws + 640000);  // 4096 B
    unsigned long long* mask_ws  = (unsigned long long*)(ws + 644096);  // 4096000 B
    // overlays inside the mask region (all consumed before mask_kernel writes):
    unsigned int* ghist = (unsigned int*)(ws + 644096);                 // 512 KB
    unsigned long long* gcand = (unsigned long long*)(ws + 1168384);    // 512 KB
    unsigned int* gcnt  = (unsigned int*)(ws + 1692672);                // 128 B

    zero_kernel<<<129, 256, 0, stream>>>((uint4*)ghist, (uint4*)gcnt);
    hist_kernel<<<BATCH * 16, 256, 0, stream>>>(obj, ghist);
    gather_kernel<<<BATCH * 8, 1024, 0, stream>>>(obj, ghist, gcand, gcnt);
    sort_decode_kernel<<<BATCH, 1024, 0, stream>>>(deltas, anchors, imh, imw,
                                                   gcand, gcnt, boxes_ws, prob_ws, valid_ws);
    mask_kernel<<<BATCH * 8, 1024, 0, stream>>>(boxes_ws, mask_ws);
    nms_out_kernel<<<BATCH, 1024, 0, stream>>>(boxes_ws, prob_ws, valid_ws, mask_ws, out);
}

// Round 5
// 175.893 us; speedup vs baseline: 3.3159x; 1.1038x over previous
//
#include <hip/hip_runtime.h>
#include <math.h>

#define BATCH 32
#define A_PER 9
#define FH 100
#define FW 100
#define A_TOT (FH*FW*A_PER)   /* 90000 */
#define KSEL 1000
#define BUFCAP 2048
#define NBIN 4096             /* 12-bit prefix histogram */
#define NMS_T 0.7f
#define MIN_SZ 0.001f
#define BBOX_CLIP_F 4.135166556742356f

__device__ __forceinline__ unsigned int f2key(float f) {
    unsigned int u = __float_as_uint(f);
    return u ^ ((u & 0x80000000u) ? 0xFFFFFFFFu : 0x80000000u);
}
__device__ __forceinline__ float key2f(unsigned int k) {
    return __uint_as_float((k & 0x80000000u) ? (k ^ 0x80000000u) : ~k);
}

// ------- Kernel 0: zero ghist + gcand + counters + valid bits ---------------
__global__ __launch_bounds__(256) void zero_kernel(
    uint4* __restrict__ ghist4, uint4* __restrict__ gcand4,
    uint4* __restrict__ gcnt4, uint4* __restrict__ valid4)
{
    const uint4 z = make_uint4(0u, 0u, 0u, 0u);
    int bid = blockIdx.x;
    if (bid < 128) {
        ghist4[bid * 256 + threadIdx.x] = z;
    } else if (bid < 256) {
        gcand4[(bid - 128) * 256 + threadIdx.x] = z;
    } else if (bid == 256) {
        if (threadIdx.x < 8) gcnt4[threadIdx.x] = z;
    } else {
        valid4[threadIdx.x] = z;          // 256 * 16 B = 4096 B
    }
}

// ---------------- Kernel 1: per-image 4096-bin histogram (16 blocks/image) --
__global__ __launch_bounds__(256) void hist_kernel(
    const float* __restrict__ obj, unsigned int* __restrict__ ghist)
{
    const int b = blockIdx.x >> 4;
    const int part = blockIdx.x & 15;
    const int tid = threadIdx.x;
    __shared__ unsigned int h[NBIN];
    for (int i = tid; i < NBIN; i += 256) h[i] = 0u;
    __syncthreads();
    const float4* sc4 = (const float4*)(obj + (size_t)b * A_TOT);
    for (int i = part * 256 + tid; i < A_TOT / 4; i += 4096) {
        float4 v = sc4[i];
        atomicAdd(&h[f2key(v.x) >> 20], 1u);
        atomicAdd(&h[f2key(v.y) >> 20], 1u);
        atomicAdd(&h[f2key(v.z) >> 20], 1u);
        atomicAdd(&h[f2key(v.w) >> 20], 1u);
    }
    __syncthreads();
    unsigned int* gh = ghist + (size_t)b * NBIN;
    for (int i = tid; i < NBIN; i += 256)
        if (h[i]) atomicAdd(&gh[i], h[i]);
}

// ---------------- Kernel 2: threshold scan + distributed gather -------------
__global__ __launch_bounds__(1024) void gather_kernel(
    const float* __restrict__ obj, const unsigned int* __restrict__ ghist,
    unsigned long long* __restrict__ gcand, unsigned int* __restrict__ gcnt)
{
    const int b = blockIdx.x >> 3;
    const int part = blockIdx.x & 7;
    const int tid = threadIdx.x;
    const int lane = tid & 63;
    const int wv = tid >> 6;

    __shared__ unsigned int wsum[16];
    __shared__ unsigned int sh_T, lcnt, base_sh;
    __shared__ unsigned long long cbuf[BUFCAP];

    if (tid == 0) lcnt = 0u;

    // ---- threshold bin T: largest bin with suffix-count crossing 1000 ----
    const unsigned int* gh = ghist + (size_t)b * NBIN;
    unsigned int h0 = gh[tid * 4 + 0], h1 = gh[tid * 4 + 1];
    unsigned int h2 = gh[tid * 4 + 2], h3 = gh[tid * 4 + 3];
    unsigned int ts = h0 + h1 + h2 + h3;
    unsigned int x = ts;
#pragma unroll
    for (int off = 1; off < 64; off <<= 1) {
        unsigned int v = __shfl_down(x, off);
        if (lane + off < 64) x += v;
    }
    if (lane == 0) wsum[wv] = x;
    __syncthreads();
    unsigned int swave = 0;
    for (int q = wv + 1; q < 16; ++q) swave += wsum[q];
    unsigned int S_hi = swave + (x - ts);
    unsigned int a3 = S_hi;
    unsigned int a2 = a3 + h3;
    unsigned int a1 = a2 + h2;
    unsigned int a0 = a1 + h1;
    if (a3 < KSEL && a3 + h3 >= KSEL) sh_T = (unsigned)(tid * 4 + 3);
    if (a2 < KSEL && a2 + h2 >= KSEL) sh_T = (unsigned)(tid * 4 + 2);
    if (a1 < KSEL && a1 + h1 >= KSEL) sh_T = (unsigned)(tid * 4 + 1);
    if (a0 < KSEL && a0 + h0 >= KSEL) sh_T = (unsigned)(tid * 4 + 0);
    __syncthreads();
    unsigned int T = sh_T;

    // ---- scan this block's 1/8 slice, stage candidates in LDS ----
    const float4* sc4 = (const float4*)(obj + (size_t)b * A_TOT);
#pragma unroll
    for (int j = 0; j < 3; ++j) {
        int i4 = j * 8192 + part * 1024 + tid;
        if (i4 < A_TOT / 4) {
            float4 v = sc4[i4];
            float vs[4] = {v.x, v.y, v.z, v.w};
#pragma unroll
            for (int c = 0; c < 4; ++c) {
                unsigned int key = f2key(vs[c]);
                if ((key >> 20) >= T) {
                    unsigned int pos = atomicAdd(&lcnt, 1u);
                    if (pos < BUFCAP) {
                        int e = i4 * 4 + c;
                        int a = e / 10000; int rem = e - a * 10000;   // rem=h*100+w
                        unsigned int i = (unsigned int)(rem * 9 + a); // flat (h,w,a)
                        cbuf[pos] = ((unsigned long long)key << 32) | (unsigned int)(~i);
                    }
                }
            }
        }
    }
    __syncthreads();
    if (tid == 0) base_sh = atomicAdd(&gcnt[b], lcnt);
    __syncthreads();
    unsigned int base = base_sh, n = lcnt;
    for (unsigned int i = tid; i < n; i += 1024) {
        unsigned int p = base + i;
        if (p < BUFCAP) gcand[(size_t)b * BUFCAP + p] = cbuf[i];
    }
}

// -------- Kernel 3: exact rank (all-pairs count) + decode + scatter ---------
__global__ __launch_bounds__(256) void rank_decode_kernel(
    const float* __restrict__ deltas,
    const float* __restrict__ anchors,
    const int* __restrict__ imh_p, const int* __restrict__ imw_p,
    const unsigned long long* __restrict__ gcand,
    const unsigned int* __restrict__ gcnt,
    float* __restrict__ boxes_ws, float* __restrict__ prob_ws,
    unsigned long long* __restrict__ valid_ws)
{
    const int b = blockIdx.x >> 3;
    const int part = blockIdx.x & 7;
    const int tid = threadIdx.x;
    const int lane = tid & 63;

    unsigned int cnt = gcnt[b]; if (cnt > BUFCAP) cnt = BUFCAP;
    const unsigned long long* gc = gcand + (size_t)b * BUFCAP;
    const int c = part * 256 + tid;          // 0..2047, always in range
    unsigned long long my = gc[c];           // zero-padded beyond cnt
    bool active = (c < (int)cnt);

    // rank = #{j : key_j > key_i}; keys unique -> exact sorted position.
    // Wave-tile scan: 1 coalesced load of 64 keys, then 64 readlane
    // broadcasts (VALU pipe only) with u64 compare + carry add.
    unsigned int ntile = (cnt + 63u) >> 6;   // padded zeros never outrank
    unsigned int rank = 0;
    for (unsigned int t0 = 0; t0 < ntile; ++t0) {
        unsigned long long kk = gc[t0 * 64 + lane];
        unsigned int lo = (unsigned int)kk, hi = (unsigned int)(kk >> 32);
#pragma unroll
        for (int t = 0; t < 64; ++t) {
            unsigned int khi = __builtin_amdgcn_readlane(hi, t);
            unsigned int klo = __builtin_amdgcn_readlane(lo, t);
            unsigned long long kj = ((unsigned long long)khi << 32) | klo;
            rank += (kj > my) ? 1u : 0u;
        }
    }

    if (active && rank < KSEL) {
        unsigned int keyhi = (unsigned int)(my >> 32);
        unsigned int i = ~((unsigned int)my);
        float score = key2f(keyhi);
        float prob = 1.0f / (1.0f + expf(-score));

        int a = (int)(i % 9u); int hw = (int)(i / 9u);
        int h = hw / 100, w = hw - 100 * (hw / 100);
        const float* D = deltas + (size_t)b * 36 * 10000;
        int off = h * 100 + w;
        float dx  = D[(a * 4 + 0) * 10000 + off];
        float dy  = D[(a * 4 + 1) * 10000 + off];
        float dwv = fminf(D[(a * 4 + 2) * 10000 + off], BBOX_CLIP_F);
        float dhv = fminf(D[(a * 4 + 3) * 10000 + off], BBOX_CLIP_F);
        const float* anc = anchors + (size_t)i * 4;
        float ax1 = anc[0], ay1 = anc[1], ax2 = anc[2], ay2 = anc[3];
        float aw = ax2 - ax1, ah = ay2 - ay1;
        float acx = ax1 + 0.5f * aw, acy = ay1 + 0.5f * ah;
        float pcx = dx * aw + acx, pcy = dy * ah + acy;
        float pw = expf(dwv) * aw, ph = expf(dhv) * ah;
        float imw = (float)(*imw_p);
        float imh = (float)(*imh_p);
        float x1 = pcx - 0.5f * pw, y1 = pcy - 0.5f * ph;
        float x2 = pcx + 0.5f * pw, y2 = pcy + 0.5f * ph;
        x1 = fminf(fmaxf(x1, 0.0f), imw);
        y1 = fminf(fmaxf(y1, 0.0f), imh);
        x2 = fminf(fmaxf(x2, 0.0f), imw);
        y2 = fminf(fmaxf(y2, 0.0f), imh);
        bool valid = ((x2 - x1) >= MIN_SZ) && ((y2 - y1) >= MIN_SZ) && (prob >= 0.0f);
        ((float4*)boxes_ws)[(size_t)b * KSEL + rank] = make_float4(x1, y1, x2, y2);
        prob_ws[(size_t)b * KSEL + rank] = prob;
        if (valid)
            atomicOr(&valid_ws[b * 16 + (rank >> 6)], 1ull << (rank & 63));
    }
}

// ---------------- Kernel 4: 1000x1000 suppression bitmatrix ----------------
__global__ __launch_bounds__(1024) void mask_kernel(
    const float* __restrict__ boxes_ws, unsigned long long* __restrict__ mask_ws)
{
    const int b = blockIdx.x >> 3;
    const int part = blockIdx.x & 7;
    const int tid = threadIdx.x;
    const int lane = tid & 63;
    const int wv = tid >> 6;          // 0..15
    __shared__ float4 bx[KSEL];
    __shared__ float ar[KSEL];
    for (int r = tid; r < KSEL; r += 1024) {
        float4 v = ((const float4*)boxes_ws)[(size_t)b * KSEL + r];
        bx[r] = v;
        ar[r] = (v.z - v.x) * (v.w - v.y);
    }
    __syncthreads();
    int slot = part * 16 + wv;        // 0..127
    for (int r = slot; r < KSEL; r += 128) {
        float4 a = bx[r];
        float area_a = ar[r];
        unsigned long long* row = mask_ws + ((size_t)b * KSEL + r) * 16;
        int wlo = r >> 6;
        for (int t = 0; t < 16; ++t) {
            if (t < wlo) { if (lane == 0) row[t] = 0ull; continue; }
            int j = (t << 6) | lane;
            bool bit = false;
            if (j > r && j < KSEL) {
                float4 c = bx[j];
                float xx1 = fmaxf(a.x, c.x), yy1 = fmaxf(a.y, c.y);
                float xx2 = fminf(a.z, c.z), yy2 = fminf(a.w, c.w);
                float iw = fmaxf(xx2 - xx1, 0.0f), ih = fmaxf(yy2 - yy1, 0.0f);
                float inter = iw * ih;
                float iou = inter / (area_a + ar[j] - inter + 1e-12f);
                bit = iou > NMS_T;
            }
            unsigned long long m = __ballot(bit ? 1 : 0);
            if (lane == 0) row[t] = m;
        }
    }
}

// ------- Kernel 5: greedy NMS (conflict fast-path) + stable compaction -----
__global__ __launch_bounds__(1024) void nms_out_kernel(
    const float* __restrict__ boxes_ws, const float* __restrict__ prob_ws,
    const unsigned long long* __restrict__ valid_ws,
    const unsigned long long* __restrict__ mask_ws,
    float* __restrict__ out)
{
    const int b = blockIdx.x;
    const int tid = threadIdx.x;
    const int lane = tid & 63;
    const int wv = tid >> 6;

    __shared__ unsigned long long partial[16];
    __shared__ unsigned long long keepw_sh[16];
    __shared__ unsigned int psum[16];
    __shared__ int klist[1024];
    __shared__ int cnt_sh;

    const unsigned long long* M = mask_ws + (size_t)b * KSEL * 16;

    // wave 0: diagonal 64x64 blocks + validity words in registers
    unsigned long long Dd[16];
    unsigned long long validw = 0ull;
    if (wv == 0) {
#pragma unroll
        for (int w = 0; w < 16; ++w) {
            int row = w * 64 + lane;
            Dd[w] = (row < KSEL) ? M[(size_t)row * 16 + w] : 0ull;
        }
        validw = (lane < 16) ? valid_ws[b * 16 + lane] : 0ull;
    }
    if (tid == 0) { cnt_sh = 0; klist[0] = 0; }
    __syncthreads();

#pragma unroll
    for (int w = 0; w < 16; ++w) {
        // --- cooperative cross-word suppression gather: wave wv does batch wv ---
        int cnt = cnt_sh;
        int j = wv * 64 + lane;
        int jj = (j < cnt) ? j : 0;
        int kidx = klist[jj];
        unsigned long long v = M[(size_t)kidx * 16 + w];
        if (j >= cnt) v = 0ull;
#pragma unroll
        for (int off = 32; off > 0; off >>= 1) v |= __shfl_xor(v, off);
        if (lane == 0) partial[wv] = v;
        __syncthreads();

        if (wv == 0) {
            unsigned long long sup = (lane < 16) ? partial[lane] : 0ull;
#pragma unroll
            for (int off = 32; off > 0; off >>= 1) sup |= __shfl_xor(sup, off);
            unsigned long long cw = __shfl(validw, w) & ~sup;
            unsigned long long Dw = Dd[w];
            unsigned long long keptw = 0ull;
            while (cw) {
                unsigned long long myrow = Dw & cw;   // who I'd suppress among candidates
                unsigned long long confl =
                    __ballot((((cw >> lane) & 1ull) && myrow != 0ull) ? 1 : 0);
                if (confl == 0ull) { keptw |= cw; break; }     // fast path: keep all
                int c = __ffsll((long long)confl) - 1;
                unsigned long long le = (c == 63) ? ~0ull : ((1ull << (c + 1)) - 1ull);
                keptw |= cw & le;                     // all candidates <= c kept
                unsigned long long Dc = __shfl(Dw, c);
                cw &= ~le & ~Dc;                      // drop suppressed, continue above c
            }
            // append kept indices to klist (parallel rank write)
            if ((keptw >> lane) & 1ull) {
                int rank = (int)__popcll(keptw & ((1ull << lane) - 1ull));
                klist[cnt + rank] = w * 64 + lane;
            }
            if (lane == 0) {
                keepw_sh[w] = keptw;
                cnt_sh = cnt + (int)__popcll(keptw);
            }
        }
        __syncthreads();
    }

    if (tid == 0) {
        unsigned int s = 0;
        for (int wq = 0; wq < 16; ++wq) { psum[wq] = s; s += __popcll(keepw_sh[wq]); }
    }
    __syncthreads();

    float* ob = out;                                     // [B,1000,4]
    float* op = out + (size_t)BATCH * KSEL * 4;          // [B,1000]
    float* om = op + (size_t)BATCH * KSEL;               // [B,1000]
    float* obb = ob + (size_t)b * KSEL * 4;
    float* opb = op + (size_t)b * KSEL;
    float* omb = om + (size_t)b * KSEL;

    for (int r = tid; r < KSEL; r += 1024) {
        obb[r * 4 + 0] = 0.0f; obb[r * 4 + 1] = 0.0f;
        obb[r * 4 + 2] = 0.0f; obb[r * 4 + 3] = 0.0f;
        opb[r] = 0.0f; omb[r] = 0.0f;
    }
    __syncthreads();
    for (int r = tid; r < KSEL; r += 1024) {
        unsigned long long kw = keepw_sh[r >> 6];
        if ((kw >> (r & 63)) & 1ull) {
            unsigned int p = psum[r >> 6] + (unsigned int)__popcll(kw & ((1ull << (r & 63)) - 1ull));
            size_t src = ((size_t)b * KSEL + r) * 4;
            obb[p * 4 + 0] = boxes_ws[src + 0];
            obb[p * 4 + 1] = boxes_ws[src + 1];
            obb[p * 4 + 2] = boxes_ws[src + 2];
            obb[p * 4 + 3] = boxes_ws[src + 3];
            opb[p] = prob_ws[(size_t)b * KSEL + r];
            omb[p] = 1.0f;
        }
    }
}

extern "C" void kernel_launch(void* const* d_in, const int* in_sizes, int n_in,
                              void* d_out, int out_size, void* d_ws, size_t ws_size,
                              hipStream_t stream) {
    const float* obj     = (const float*)d_in[0];
    const float* deltas  = (const float*)d_in[1];
    const float* anchors = (const float*)d_in[2];
    const int*   imh     = (const int*)d_in[3];
    const int*   imw     = (const int*)d_in[4];
    float* out = (float*)d_out;

    char* ws = (char*)d_ws;
    float* boxes_ws = (float*)ws;                                       // 512000 B
    float* prob_ws  = (float*)(ws + 512000);                            // 128000 B
    unsigned long long* valid_ws = (unsigned long long*)(ws + 640000);  // 4096 B
    unsigned long long* mask_ws  = (unsigned long long*)(ws + 644096);  // 4096000 B
    // overlays inside the mask region (all consumed before mask_kernel writes):
    unsigned int* ghist = (unsigned int*)(ws + 644096);                 // 512 KB
    unsigned long long* gcand = (unsigned long long*)(ws + 1168384);    // 512 KB
    unsigned int* gcnt  = (unsigned int*)(ws + 1692672);                // 128 B

    zero_kernel<<<258, 256, 0, stream>>>((uint4*)ghist, (uint4*)gcand,
                                         (uint4*)gcnt, (uint4*)valid_ws);
    hist_kernel<<<BATCH * 16, 256, 0, stream>>>(obj, ghist);
    gather_kernel<<<BATCH * 8, 1024, 0, stream>>>(obj, ghist, gcand, gcnt);
    rank_decode_kernel<<<BATCH * 8, 256, 0, stream>>>(deltas, anchors, imh, imw,
                                                      gcand, gcnt, boxes_ws, prob_ws, valid_ws);
    mask_kernel<<<BATCH * 8, 1024, 0, stream>>>(boxes_ws, mask_ws);
    nms_out_kernel<<<BATCH, 1024, 0, stream>>>(boxes_ws, prob_ws, valid_ws, mask_ws, out);
}